// Round 10
// baseline (85.587 us; speedup 1.0000x reference)
//
#include <hip/hip_runtime.h>

// Problem constants (from reference)
constexpr int B = 128, T = 12, V = 512, P = 40;
constexpr int CHUNKS = 4;        // V split across 4 blocks per batch
constexpr int VPB = V / CHUNKS;  // 128 v's per block, 2 v's per thread
#define MAP_THRESH 0.5f
#define DIS_THRESH 1.0f
#define MASK_FILL  1000000.0f

// Lessons: R4 — agent-scope fences ~90 us, never. R9 — single dispatch w/
// atomicExch handoff + validity-gated spins works, bit-exact. R10 — ensure
// producer->consumer dispatch order and guaranteed co-residency (512 blocks
// = 2/CU), double per-thread MLP (10 hoisted float4 loads).

// transform: x = l*30 - 15 ; y = l*60 - 30  (two-step rounding, no FMA, matches np)
__device__ __forceinline__ float txf(float l) { return __fadd_rn(__fmul_rn(l, 30.0f), -15.0f); }
__device__ __forceinline__ float tyf(float l) { return __fadd_rn(__fmul_rn(l, 60.0f), -30.0f); }

// block-uniform float -> SGPR
__device__ __forceinline__ float rfl(float x) {
    return __int_as_float(__builtin_amdgcn_readfirstlane(__float_as_int(x)));
}

__device__ __forceinline__ unsigned long long ld_agent_u64(const unsigned long long* p) {
    return __hip_atomic_load(p, __ATOMIC_RELAXED, __HIP_MEMORY_SCOPE_AGENT);
}

#define FIXED_SCALE 1099511627776.0   /* 2^40 */
#define PART_BIAS   (1ULL << 45)

// packed min slot: ((bits(sd)+1) << 32) | v.  bits+1 is order-preserving for
// sd>=0 and makes high32>=1, so u64 order == (val, first-idx) rule and the
// value 0 / poison 0xAA.. / any low32>=512 are recognizably invalid.
__device__ __forceinline__ bool slot_valid(unsigned long long x) {
    return ((x & 0xffffffffULL) < (unsigned long long)V) &&
           (((x >> 32) - 1ULL) <= 0x7F800000ULL) && ((x >> 32) != 0ULL);
}
__device__ __forceinline__ bool part_valid(unsigned long long x) {
    return x >= PART_BIAS && x < (PART_BIAS << 1);
}

// Single kernel, grid = B*CHUNKS = 512 blocks x 256 (2 blocks/CU guaranteed
// co-resident; consumer block c==3 of each b dispatches after its producers).
// Phase A (all blocks): per-t packed min over 128 v's -> atomicExch into slots.
// Phase B (c==3 block per b): validity-spin on 4 chunk slots per t,
//   intersections, weighted sum -> biased fixed-point atomicExch into part[b].
// Phase C (block b==0,c==3): lanes spin-read part[0..127], exact u64 sum, out.
__global__ __launch_bounds__(256) void k_all(
    const float* __restrict__ ego,     // B,T,2
    const float* __restrict__ lanes,   // B,V,P,2
    const float* __restrict__ scores,  // B,V,3
    const float* __restrict__ weight,  // B,T
    unsigned long long* __restrict__ ws_min,  // B*T*CHUNKS slots
    unsigned long long* __restrict__ part,    // B
    float* __restrict__ out)
{
    const int blk = blockIdx.x;
    const int b = blk / CHUNKS, c = blk % CHUNKS;
    const int tid = threadIdx.x;
    const int wid = tid >> 6, lane = tid & 63;
    const int vl = tid >> 2;   // 0..63
    const int pp = tid & 3;    // float4s {pp, 4+pp, 8+pp, 12+pp, 16+pp}
    const int v0 = c * VPB + vl;        // first v of this thread
    const int v1 = v0 + 64;             // second v of this thread

    // ---- issue ALL global loads first (unconditional -> 12 in flight) ----
    const float sc0 = scores[(size_t)(b * V + v0) * 3 + 2];
    const float sc1 = scores[(size_t)(b * V + v1) * 3 + 2];
    const float4* lp0 = (const float4*)(lanes + (size_t)(b * V + v0) * P * 2);
    const float4* lp1 = (const float4*)(lanes + (size_t)(b * V + v1) * P * 2);
    float4 a0 = lp0[pp],      a1 = lp0[4 + pp],  a2 = lp0[8 + pp];
    float4 a3 = lp0[12 + pp], a4 = lp0[16 + pp];
    float4 b0 = lp1[pp],      b1 = lp1[4 + pp],  b2 = lp1[8 + pp];
    float4 b3 = lp1[12 + pp], b4 = lp1[16 + pp];

    // ---- wave-parallel ego cumsum (overlaps the lane loads above) ----
    __shared__ float s_px[T + 1], s_py[T + 1];
    __shared__ float s_w[T];
    __shared__ int   s_cross[T];
    if (wid == 0) {
        float e = (lane < 2 * T) ? ego[b * 2 * T + lane] : 0.f;
        float cx = 0.f, cy = 0.f;
#pragma unroll
        for (int k = 0; k < T; ++k) {  // exact left-to-right fp32 cumsum
            float vx = __shfl(e, 2 * k);
            float vy = __shfl(e, 2 * k + 1);
            if (k <= lane) { cx = __fadd_rn(cx, vx); cy = __fadd_rn(cy, vy); }
        }
        if (lane == 0) { s_px[0] = 0.f; s_py[0] = 0.f; }
        if (lane < T)  { s_px[lane + 1] = cx; s_py[lane + 1] = cy; }
    } else if (wid == 1) {
        if (lane < T) s_w[lane] = weight[b * T + lane];
        else if (lane < 2 * T) s_cross[lane - T] = 0;
    }
    __syncthreads();

    // block-uniform trajectory -> SGPRs
    float px[T], py[T];
#pragma unroll
    for (int t = 0; t < T; ++t) { px[t] = rfl(s_px[t + 1]); py[t] = rfl(s_py[t + 1]); }

    // ---- Phase A: distances for v0 then v1 ----
    float ms0[T], ms1[T];
#pragma unroll
    for (int t = 0; t < T; ++t) { ms0[t] = 3.4e38f; ms1[t] = 3.4e38f; }
    {
        const float4 fa[5] = {a0, a1, a2, a3, a4};
#pragma unroll
        for (int j = 0; j < 5; ++j) {
            float x0 = txf(fa[j].x), y0 = tyf(fa[j].y);
            float x1 = txf(fa[j].z), y1 = tyf(fa[j].w);
#pragma unroll
            for (int t = 0; t < T; ++t) {
                float dx = __fsub_rn(px[t], x0);
                float dy = __fsub_rn(py[t], y0);
                float d2 = __fadd_rn(__fmul_rn(dx, dx), __fmul_rn(dy, dy));
                ms0[t] = fminf(ms0[t], d2);
                dx = __fsub_rn(px[t], x1);
                dy = __fsub_rn(py[t], y1);
                d2 = __fadd_rn(__fmul_rn(dx, dx), __fmul_rn(dy, dy));
                ms0[t] = fminf(ms0[t], d2);
            }
        }
        const float4 fb[5] = {b0, b1, b2, b3, b4};
#pragma unroll
        for (int j = 0; j < 5; ++j) {
            float x0 = txf(fb[j].x), y0 = tyf(fb[j].y);
            float x1 = txf(fb[j].z), y1 = tyf(fb[j].w);
#pragma unroll
            for (int t = 0; t < T; ++t) {
                float dx = __fsub_rn(px[t], x0);
                float dy = __fsub_rn(py[t], y0);
                float d2 = __fadd_rn(__fmul_rn(dx, dx), __fmul_rn(dy, dy));
                ms1[t] = fminf(ms1[t], d2);
                dx = __fsub_rn(px[t], x1);
                dy = __fsub_rn(py[t], y1);
                d2 = __fadd_rn(__fmul_rn(dx, dx), __fmul_rn(dy, dy));
                ms1[t] = fminf(ms1[t], d2);
            }
        }
    }
    if (sc0 < MAP_THRESH) {  // masked: all P points are exactly (1e6, 1e6)
#pragma unroll
        for (int t = 0; t < T; ++t) {
            float dx = __fsub_rn(px[t], MASK_FILL);
            float dy = __fsub_rn(py[t], MASK_FILL);
            ms0[t] = __fadd_rn(__fmul_rn(dx, dx), __fmul_rn(dy, dy));
        }
    }
    if (sc1 < MAP_THRESH) {
#pragma unroll
        for (int t = 0; t < T; ++t) {
            float dx = __fsub_rn(px[t], MASK_FILL);
            float dy = __fsub_rn(py[t], MASK_FILL);
            ms1[t] = __fadd_rn(__fmul_rn(dx, dx), __fmul_rn(dy, dy));
        }
    }

    // combine the 4 point-chunks of each v (adjacent lanes share a v)
#pragma unroll
    for (int t = 0; t < T; ++t) {
        ms0[t] = fminf(ms0[t], __shfl_xor(ms0[t], 1));
        ms0[t] = fminf(ms0[t], __shfl_xor(ms0[t], 2));
        ms1[t] = fminf(ms1[t], __shfl_xor(ms1[t], 1));
        ms1[t] = fminf(ms1[t], __shfl_xor(ms1[t], 2));
    }

    // sqrt monotone under RN: sqrt(min)==min(sqrt). Pack ((bits+1)<<32)|v; u64
    // order == (val, first-idx) lexicographic rule; fold this thread's 2 v's.
    unsigned long long pk[T];
#pragma unroll
    for (int t = 0; t < T; ++t) {
        unsigned long long q0 =
            (((unsigned long long)__float_as_uint(sqrtf(ms0[t])) + 1ULL) << 32) | (unsigned)v0;
        unsigned long long q1 =
            (((unsigned long long)__float_as_uint(sqrtf(ms1[t])) + 1ULL) << 32) | (unsigned)v1;
        pk[t] = (q1 < q0) ? q1 : q0;
    }

    // in-wave butterfly over the 16 v-slots of this wave (u64 min)
#pragma unroll
    for (int d = 4; d <= 32; d <<= 1) {
#pragma unroll
        for (int t = 0; t < T; ++t) {
            unsigned long long o =
                ((unsigned long long)(unsigned)__shfl_xor((int)(pk[t] >> 32), d) << 32) |
                (unsigned)__shfl_xor((int)(pk[t] & 0xffffffffu), d);
            pk[t] = (o < pk[t]) ? o : pk[t];
        }
    }
    __shared__ unsigned long long wmin[T][4];
    if (lane == 0) {
#pragma unroll
        for (int t = 0; t < T; ++t) wmin[t][wid] = pk[t];
    }
    __syncthreads();
    if (tid < T) {
        unsigned long long m = wmin[tid][0];
#pragma unroll
        for (int w = 1; w < 4; ++w) m = (wmin[tid][w] < m) ? wmin[tid][w] : m;
        // device-scope RMW -> coherent at L2 coherence point, cross-XCD safe
        atomicExch(&ws_min[(b * T + tid) * CHUNKS + c], m);
    }

    if (c != CHUNKS - 1) return;   // producers exit; consumer has highest blk of b

    // ---------------- Phase B (one block per b) ----------------
    __shared__ unsigned long long s_m[T][CHUNKS];
    __shared__ float s_md[T];
    __shared__ int   s_vm[T];
    if (tid < T * CHUNKS) {   // 48 lanes: validity-gated spin on chunk slots
        int t = tid >> 2, cc = tid & 3;
        const unsigned long long* p = &ws_min[(b * T + t) * CHUNKS + cc];
        unsigned long long x = ld_agent_u64(p);
        while (!slot_valid(x)) { __builtin_amdgcn_s_sleep(2); x = ld_agent_u64(p); }
        s_m[t][cc] = x;
    }
    __syncthreads();
    if (tid < T) {
        unsigned long long m = s_m[tid][0];
#pragma unroll
        for (int cc = 1; cc < CHUNKS; ++cc)  // u64 min == (val, first-idx) rule
            m = (s_m[tid][cc] < m) ? s_m[tid][cc] : m;
        s_md[tid] = __uint_as_float((unsigned)((m >> 32) - 1ULL));
        s_vm[tid] = (int)(m & 0xffffffffu);
    }
    __syncthreads();

    // 12 x 39 intersection tests (lanes/scores are pristine inputs: plain loads)
    for (int w = tid; w < T * (P - 1); w += 256) {
        int t = w / (P - 1), p = w % (P - 1);
        int vw = s_vm[t];
        // masked lane -> all points identical -> det == 0 -> never intersects
        if (scores[(size_t)(b * V + vw) * 3 + 2] < MAP_THRESH) continue;
        const float* lq = lanes + (size_t)(b * V + vw) * P * 2 + (size_t)p * 2;
        float bx0 = txf(lq[0]), by0 = tyf(lq[1]);
        float bx1 = txf(lq[2]), by1 = tyf(lq[3]);
        float sx = s_px[t],     sy = s_py[t];      // starts[t]
        float ex = s_px[t + 1], ey = s_py[t + 1];  // pred[t]
        float d1x = __fsub_rn(ex, sx),  d1y = __fsub_rn(ey, sy);
        float d2x = __fsub_rn(bx1, bx0), d2y = __fsub_rn(by1, by0);
        float det = __fsub_rn(__fmul_rn(d1x, d2y), __fmul_rn(d2x, d1y));
        if (det != 0.0f) {
            float dx = __fsub_rn(bx0, sx), dy = __fsub_rn(by0, sy);
            float t1 = __fdiv_rn(__fsub_rn(__fmul_rn(dx, d2y), __fmul_rn(dy, d2x)), det);
            float t2 = __fdiv_rn(__fsub_rn(__fmul_rn(dx, d1y), __fmul_rn(dy, d1x)), det);
            if (t1 >= 0.f && t1 <= 1.f && t2 >= 0.f && t2 <= 1.f)
                atomicOr(&s_cross[t], 1);  // LDS atomic, block-local
        }
    }
    __syncthreads();

    if (tid == 0) {
        float sum = 0.f;
        int crossed = 0;
#pragma unroll
        for (int t = 0; t < T; ++t) {
            crossed |= s_cross[t];  // cumsum(intersect) >= 1
            float md = s_md[t];
            float l = (md <= DIS_THRESH) ? __fsub_rn(DIS_THRESH, md) : 0.f;
            if (crossed) l = 0.f;
            sum = __fadd_rn(sum, __fmul_rn(l, s_w[t]));
        }
        // biased fixed-point partial: q + 2^45 in [2^45, 2^46) -> poison/zero invalid
        unsigned long long q = (unsigned long long)((double)sum * FIXED_SCALE + 0.5);
        atomicExch(&part[b], q + PART_BIAS);
    }

    if (b != 0) return;   // only block (0, CHUNKS-1) finalizes

    // ---------------- Phase C: exact integer sum of 128 partials ----------------
    __shared__ unsigned long long s_part[B];
    if (tid < B) {
        const unsigned long long* p = &part[tid];
        unsigned long long x = ld_agent_u64(p);
        while (!part_valid(x)) { __builtin_amdgcn_s_sleep(2); x = ld_agent_u64(p); }
        s_part[tid] = x;
    }
    __syncthreads();
    if (tid == 0) {
        unsigned long long tot = 0ULL;
#pragma unroll
        for (int i = 0; i < B; ++i) tot += s_part[i];   // exact integer sum
        tot -= (unsigned long long)B * PART_BIAS;
        out[0] = (float)((double)tot * (1.0 / FIXED_SCALE) / (double)(B * T));
    }
}

extern "C" void kernel_launch(void* const* d_in, const int* in_sizes, int n_in,
                              void* d_out, int out_size, void* d_ws, size_t ws_size,
                              hipStream_t stream) {
    const float* ego    = (const float*)d_in[0];  // B,T,2
    const float* lanes  = (const float*)d_in[1];  // B,V,P,2
    const float* scores = (const float*)d_in[2];  // B,V,3
    const float* weight = (const float*)d_in[3];  // B,T
    float* out = (float*)d_out;

    unsigned long long* ws_min = (unsigned long long*)d_ws;        // B*T*CHUNKS u64
    unsigned long long* part   = ws_min + (size_t)B * T * CHUNKS;  // B u64

    k_all<<<B * CHUNKS, 256, 0, stream>>>(ego, lanes, scores, weight, ws_min, part, out);
}